// Round 1
// 1260.086 us; speedup vs baseline: 1.2648x; 1.2648x over previous
//
#include <hip/hip_runtime.h>
#include <hip/hip_bf16.h>
#include <stdint.h>

#define N_NODES 10000
#define N_EDGES 640000
#define KPAD    10016   // K=10000 padded to mult of 32 for B staging
#define NSPLIT  4       // split-K factor for GEMM1

typedef __bf16 bf16x8 __attribute__((ext_vector_type(8)));
typedef float  f32x4  __attribute__((ext_vector_type(4)));

// ---- workspace layout (bytes) ----
#define OFF_CNT   0          // 10000 ints
#define OFF_FLAG  40960      // 1 int (int64-sniff flag)
#define OFF_DINV  65536      // 10000 floats
#define OFF_RS    131072     // 10001 ints (row_start)
#define OFF_CUR   196608     // 10000 ints (cursor)
#define OFF_CSR   262144     // 640000 ints -> end 2,822,144
#define OFF_EMBT  3145728    // 256*KPAD bf16 = 5,128,192 -> end 8,273,920; g1 reuses this
#define OFF_P     8388608    // NSPLIT * 10000*256 fp32 = 40,960,000 -> end 49,348,608
#define OFF_H2    49348608   // 10000*64 fp32 -> end 51,908,608
#define OFF_G2    51908608   // 10000*32 fp32 -> end 53,188,608
#define OFF_H3    53188608   // 10000*32 fp32 -> end 54,468,608

__device__ __forceinline__ unsigned short f2b(float f) {   // fp32 -> bf16 RNE
    unsigned int v = __float_as_uint(f);
    unsigned int r = (v + 0x7FFFu + ((v >> 16) & 1u)) >> 16;
    return (unsigned short)r;
}

// Detect int64 edge_index layout: if odd int32 words of the first 128 entries are
// all zero, data is little-endian int64 (values in [0,10000) -> high words 0).
__global__ void k_sniff(const int* __restrict__ edge, int* __restrict__ flag) {
    if (threadIdx.x == 0 && blockIdx.x == 0) {
        int f = 1;
        for (int i = 1; i < 256; i += 2) if (edge[i] != 0) { f = 0; break; }
        *flag = f;
    }
}

__global__ void k_count(const int* __restrict__ edge, const int* __restrict__ flag,
                        int* __restrict__ cnt) {
    int e = blockIdx.x * 256 + threadIdx.x;   // grid exactly 640000 threads
    int f = *flag;
    const int* dstp = edge + (f ? 2 * N_EDGES : N_EDGES);
    atomicAdd(&cnt[dstp[e << f]], 1);
}

__global__ void k_dinv(const int* __restrict__ cnt, float* __restrict__ dinv) {
    int i = blockIdx.x * 256 + threadIdx.x;
    if (i < N_NODES) dinv[i] = rsqrtf((float)(cnt[i] + 1));  // +1 self-loop
}

// single-wave shfl scan with load prefetch (replaces 640-barrier block scan)
__global__ void k_scan(const int* __restrict__ cnt, int* __restrict__ rs, int* __restrict__ cur) {
    int lane = threadIdx.x;   // 64 threads
    if (lane == 0) rs[0] = 0;
    int carry = 0;
    int v = (lane < N_NODES) ? cnt[lane] : 0;
    for (int base = 0; base < N_NODES; base += 64) {
        int nxt = base + 64 + lane;
        int vn = (nxt < N_NODES && base + 64 < N_NODES) ? cnt[nxt] : 0;  // prefetch
        int s = v;
#pragma unroll
        for (int off = 1; off < 64; off <<= 1) {
            int t = __shfl_up(s, off);
            if (lane >= off) s += t;
        }
        int incl = s + carry;
        int i = base + lane;
        if (i < N_NODES) { rs[i + 1] = incl; cur[i] = incl - v; }
        carry = __shfl(incl, 63);
        v = vn;
    }
}

__global__ void k_fill(const int* __restrict__ edge, const int* __restrict__ flag,
                       int* __restrict__ cur, int* __restrict__ csr) {
    int e = blockIdx.x * 256 + threadIdx.x;
    int f = *flag;
    const int* srcp = edge;
    const int* dstp = edge + (f ? 2 * N_EDGES : N_EDGES);
    int s = srcp[e << f];
    int d = dstp[e << f];
    int pos = atomicAdd(&cur[d], 1);
    csr[pos] = s;
}

__global__ void k_padzero(unsigned short* __restrict__ embT) {
    int i = blockIdx.x * 256 + threadIdx.x;   // 4096 total
    if (i < 256 * 16) {
        int n = i >> 4, k = i & 15;
        embT[(size_t)n * KPAD + 10000 + k] = 0;
    }
}

// emb [10000,256] fp32 -> embT [256,KPAD] bf16, LDS tile transpose
__global__ void k_transpose(const float* __restrict__ emb, unsigned short* __restrict__ embT) {
    __shared__ unsigned short t[32][65];
    int r0 = blockIdx.x * 32, c0 = blockIdx.y * 64;
    int cl = threadIdx.x & 63, rl = threadIdx.x >> 6;   // rl 0..3
    for (int i = 0; i < 8; ++i) {
        int r = r0 + rl + i * 4;
        if (r < N_NODES) t[rl + i * 4][cl] = f2b(emb[(size_t)r * 256 + c0 + cl]);
    }
    __syncthreads();
    int rr = threadIdx.x & 31, cc0 = threadIdx.x >> 5;  // cc0 0..7
    int r = r0 + rr;
    if (r < N_NODES) {
        for (int j = 0; j < 8; ++j) {
            int c = cc0 * 8 + j;
            embT[(size_t)(c0 + c) * KPAD + r] = t[rr][c];
        }
    }
}

// ---- GEMM1 (split-K): P[sp] = X[:, kslice] @ emb[kslice, :]  (fp32 partials) ----
// BM=64 BN=256 BK=32; grid (157, NSPLIT); 4 waves, each 64 rows x 64 cols (4x4 MFMA tiles).
// K-steps (313 total) split {79,78,78,78}. X read exactly once overall (400 MB).
#define LDK 40

__global__ __launch_bounds__(256) void k_gemm1(
        const float* __restrict__ X,
        const unsigned short* __restrict__ embT,
        float* __restrict__ P) {
    __shared__ __align__(16) unsigned short As[64 * LDK];    // 5.0 KB
    __shared__ __align__(16) unsigned short Bs[256 * LDK];   // 20.0 KB
    const int tid = threadIdx.x;
    const int lane = tid & 63;
    const int w = tid >> 6;                  // wave 0..3 -> 64-col slice
    const int bM = blockIdx.x;
    const int sp = blockIdx.y;

    // K-step range for this split: {0..79, 79..157, 157..235, 235..313}
    const int st0 = sp * 78 + (sp > 0 ? 1 : 0);
    const int st1 = (sp + 1) * 78 + 1;

    // A staging: 256 threads, row tid>>2 (0..63), 8 floats each (2 x float4)
    const int ar = tid >> 2, ac = tid & 3;
    const int c0 = ac * 8;
    int agrow = bM * 64 + ar; if (agrow > N_NODES - 1) agrow = N_NODES - 1;
    const float* gA = X + (size_t)agrow * 10000 + c0;
    // B staging: 256 threads x 4 uint4: rows tid>>2 + {0,64,128,192}, chunk tid&3
    const int br = tid >> 2, bc = tid & 3;
    const unsigned short* gB = embT + (size_t)br * KPAD + bc * 8;

    const float4 z4 = make_float4(0.f, 0.f, 0.f, 0.f);
    int kk = st0 * 32;
    float4 pa0 = (kk + c0 + 4 <= 10000) ? *(const float4*)(gA + kk)     : z4;
    float4 pa1 = (kk + c0 + 8 <= 10000) ? *(const float4*)(gA + kk + 4) : z4;
    uint4 pb[4];
#pragma unroll
    for (int s = 0; s < 4; ++s) pb[s] = *(const uint4*)(gB + (size_t)(64 * s) * KPAD + kk);

    f32x4 acc[4][4];
#pragma unroll
    for (int i = 0; i < 4; ++i)
#pragma unroll
        for (int j = 0; j < 4; ++j) acc[i][j] = (f32x4){0.f, 0.f, 0.f, 0.f};

    const int q = lane >> 4, l16 = lane & 15;
    const unsigned short* aRd[4];
#pragma unroll
    for (int mt = 0; mt < 4; ++mt) aRd[mt] = As + (mt * 16 + l16) * LDK + q * 8;
    const unsigned short* bRd[4];
#pragma unroll
    for (int nt = 0; nt < 4; ++nt) bRd[nt] = Bs + (w * 64 + nt * 16 + l16) * LDK + q * 8;

    for (int it = st0; it < st1; ++it) {
        __syncthreads();
        {
            ushort4 a0, a1;
            a0.x = f2b(pa0.x); a0.y = f2b(pa0.y); a0.z = f2b(pa0.z); a0.w = f2b(pa0.w);
            a1.x = f2b(pa1.x); a1.y = f2b(pa1.y); a1.z = f2b(pa1.z); a1.w = f2b(pa1.w);
            *(ushort4*)(As + ar * LDK + c0)     = a0;
            *(ushort4*)(As + ar * LDK + c0 + 4) = a1;
#pragma unroll
            for (int s = 0; s < 4; ++s)
                *(uint4*)(Bs + (br + 64 * s) * LDK + bc * 8) = pb[s];
        }
        __syncthreads();
        if (it + 1 < st1) {
            const int nk = (it + 1) * 32;
            pa0 = (nk + c0 + 4 <= 10000) ? *(const float4*)(gA + nk)     : z4;
            pa1 = (nk + c0 + 8 <= 10000) ? *(const float4*)(gA + nk + 4) : z4;
#pragma unroll
            for (int s = 0; s < 4; ++s)     // embT zero-padded to KPAD -> always safe
                pb[s] = *(const uint4*)(gB + (size_t)(64 * s) * KPAD + nk);
        }
        bf16x8 av[4], bv[4];
#pragma unroll
        for (int mt = 0; mt < 4; ++mt) av[mt] = *(const bf16x8*)aRd[mt];
#pragma unroll
        for (int nt = 0; nt < 4; ++nt) bv[nt] = *(const bf16x8*)bRd[nt];
#pragma unroll
        for (int mt = 0; mt < 4; ++mt)
#pragma unroll
            for (int nt = 0; nt < 4; ++nt)
                acc[mt][nt] = __builtin_amdgcn_mfma_f32_16x16x32_bf16(av[mt], bv[nt], acc[mt][nt], 0, 0, 0);
    }

    // epilogue: C/D layout col=lane&15, row=(lane>>4)*4+reg  [m89/m91-verified]
    float* Pp = P + (size_t)sp * N_NODES * 256;
#pragma unroll
    for (int mt = 0; mt < 4; ++mt)
#pragma unroll
        for (int nt = 0; nt < 4; ++nt) {
            int col = w * 64 + nt * 16 + l16;
            int rbase = bM * 64 + mt * 16 + q * 4;
#pragma unroll
            for (int r = 0; r < 4; ++r) {
                int row = rbase + r;
                if (row < N_NODES) Pp[(size_t)row * 256 + col] = acc[mt][nt][r];
            }
        }
}

// g1[n,f] = dinv[n] * sum_k relu(P0+P1+P2+P3)[n,k] * W1[k,f]  (split-K reduce fused)
__global__ void k_lin1(const float* __restrict__ P, const float* __restrict__ W1,
                       const float* __restrict__ dinv, float* __restrict__ g1) {
    __shared__ float w1s[256 * 64];   // 64 KB
    int tid = threadIdx.x;
    for (int i = tid; i < 256 * 64; i += 256) w1s[i] = W1[i];
    __syncthreads();
    int f = tid & 63, nl = tid >> 6;
    int node = blockIdx.x * 4 + nl;
    const float* h0 = P + (size_t)node * 256;
    const float* h1 = h0 + (size_t)N_NODES * 256;
    const float* h2 = h1 + (size_t)N_NODES * 256;
    const float* h3 = h2 + (size_t)N_NODES * 256;
    float acc = 0.f;
#pragma unroll 4
    for (int k = 0; k < 256; ++k) {
        float h = (h0[k] + h1[k]) + (h2[k] + h3[k]);
        acc += fmaxf(h, 0.f) * w1s[k * 64 + f];
    }
    g1[(size_t)node * 64 + f] = acc * dinv[node];
}

// H2[n,f] = relu( dinv[n]*(g1[n,f] + sum_{s->n} g1[s,f]) + b1[f] )
__global__ void k_agg1(const float* __restrict__ g1, const int* __restrict__ rs,
                       const int* __restrict__ csr, const float* __restrict__ dinv,
                       const float* __restrict__ b1, float* __restrict__ H2) {
    int lane = threadIdx.x & 63;
    int node = blockIdx.x * 4 + (threadIdx.x >> 6);
    float acc = g1[(size_t)node * 64 + lane];
    int e0 = rs[node], e1 = rs[node + 1];
    for (int e = e0; e < e1; ++e) acc += g1[(size_t)csr[e] * 64 + lane];
    float o = dinv[node] * acc + b1[lane];
    H2[(size_t)node * 64 + lane] = fmaxf(o, 0.f);
}

__global__ void k_lin2(const float* __restrict__ H2, const float* __restrict__ W2,
                       const float* __restrict__ dinv, float* __restrict__ g2) {
    __shared__ float w2s[64 * 32];
    int tid = threadIdx.x;
    for (int i = tid; i < 64 * 32; i += 256) w2s[i] = W2[i];
    __syncthreads();
    int f = tid & 31, nl = tid >> 5;
    int node = blockIdx.x * 8 + nl;
    const float* h = H2 + (size_t)node * 64;
    float acc = 0.f;
#pragma unroll
    for (int k = 0; k < 64; ++k) acc += h[k] * w2s[k * 32 + f];
    g2[(size_t)node * 32 + f] = acc * dinv[node];
}

__global__ void k_agg2(const float* __restrict__ g2, const int* __restrict__ rs,
                       const int* __restrict__ csr, const float* __restrict__ dinv,
                       const float* __restrict__ b2, float* __restrict__ H3) {
    int lane = threadIdx.x & 63;
    int node = blockIdx.x * 4 + (threadIdx.x >> 6);
    int f = lane & 31, half = lane >> 5;
    int e0 = rs[node], e1 = rs[node + 1];
    float acc = 0.f;
    for (int e = e0 + half; e < e1; e += 2) acc += g2[(size_t)csr[e] * 32 + f];
    acc += __shfl_down(acc, 32);
    if (half == 0) {
        acc += g2[(size_t)node * 32 + f];
        float o = dinv[node] * acc + b2[f];
        H3[(size_t)node * 32 + f] = fmaxf(o, 0.f);
    }
}

__global__ void k_dec(const float* __restrict__ H3, const float* __restrict__ dW,
                      float* __restrict__ out) {
    __shared__ float dws[32 * 16];
    int tid = threadIdx.x;
    for (int i = tid; i < 512; i += 256) dws[i] = dW[i];
    __syncthreads();
    int j = tid & 15, nl = tid >> 4;
    int node = blockIdx.x * 16 + nl;
    const float* h = H3 + (size_t)node * 32;
    float acc = 0.f;
#pragma unroll
    for (int k = 0; k < 32; ++k) acc += h[k] * dws[k * 16 + j];
    out[(size_t)node * 16 + j] = acc;
}

extern "C" void kernel_launch(void* const* d_in, const int* in_sizes, int n_in,
                              void* d_out, int out_size, void* d_ws, size_t ws_size,
                              hipStream_t stream) {
    const float* X    = (const float*)d_in[0];
    const int*   edge = (const int*)d_in[1];
    const float* emb  = (const float*)d_in[2];
    const float* W1   = (const float*)d_in[3];
    const float* b1   = (const float*)d_in[4];
    const float* W2   = (const float*)d_in[5];
    const float* b2   = (const float*)d_in[6];
    const float* dW   = (const float*)d_in[7];
    float*       out  = (float*)d_out;

    char* ws = (char*)d_ws;
    int*            cnt  = (int*)(ws + OFF_CNT);
    int*            flag = (int*)(ws + OFF_FLAG);
    float*          dinv = (float*)(ws + OFF_DINV);
    int*            rs   = (int*)(ws + OFF_RS);
    int*            cur  = (int*)(ws + OFF_CUR);
    int*            csr  = (int*)(ws + OFF_CSR);
    unsigned short* embT = (unsigned short*)(ws + OFF_EMBT);
    float*          g1   = (float*)(ws + OFF_EMBT);  // reuse after GEMM1 consumed embT
    float*          P    = (float*)(ws + OFF_P);
    float*          H2   = (float*)(ws + OFF_H2);
    float*          g2   = (float*)(ws + OFF_G2);
    float*          H3   = (float*)(ws + OFF_H3);

    hipMemsetAsync(cnt, 0, N_NODES * sizeof(int), stream);

    k_sniff<<<1, 64, 0, stream>>>(edge, flag);
    k_count<<<N_EDGES / 256, 256, 0, stream>>>(edge, flag, cnt);
    k_dinv<<<(N_NODES + 255) / 256, 256, 0, stream>>>(cnt, dinv);
    k_scan<<<1, 64, 0, stream>>>(cnt, rs, cur);
    k_fill<<<N_EDGES / 256, 256, 0, stream>>>(edge, flag, cur, csr);
    k_padzero<<<16, 256, 0, stream>>>(embT);
    k_transpose<<<dim3(313, 4), 256, 0, stream>>>(emb, embT);
    k_gemm1<<<dim3(157, NSPLIT), 256, 0, stream>>>(X, embT, P);
    k_lin1<<<N_NODES / 4, 256, 0, stream>>>(P, W1, dinv, g1);
    k_agg1<<<N_NODES / 4, 256, 0, stream>>>(g1, rs, csr, dinv, b1, H2);
    k_lin2<<<N_NODES / 8, 256, 0, stream>>>(H2, W2, dinv, g2);
    k_agg2<<<N_NODES / 4, 256, 0, stream>>>(g2, rs, csr, dinv, b2, H3);
    k_dec<<<N_NODES / 16, 256, 0, stream>>>(H3, dW, out);
}

// Round 2
// 1013.279 us; speedup vs baseline: 1.5729x; 1.2436x over previous
//
#include <hip/hip_runtime.h>
#include <hip/hip_bf16.h>
#include <stdint.h>

#define N_NODES 10000
#define N_EDGES 640000
#define KPAD    10016   // K=10000 padded to mult of 32 for B staging
#define NSPLIT  8       // split-K factor for GEMM1 (== 8 XCDs)

typedef __bf16 bf16x8 __attribute__((ext_vector_type(8)));
typedef float  f32x4  __attribute__((ext_vector_type(4)));

// ---- workspace layout (bytes) ----
#define OFF_CNT   0          // 10000 ints
#define OFF_FLAG  40960      // 1 int (int64-sniff flag)
#define OFF_DINV  65536      // 10000 floats
#define OFF_RS    131072     // 10001 ints (row_start)
#define OFF_CUR   196608     // 10000 ints (cursor)
#define OFF_CSR   262144     // 640000 ints -> end 2,822,144
#define OFF_EMBT  3145728    // 256*KPAD bf16 = 5,128,192 -> end 8,273,920; g1 reuses this
#define OFF_P     8388608    // NSPLIT * 10000*256 fp32 = 81,920,000 -> end 90,308,608
#define OFF_H2    90308608   // 10000*64 fp32 -> end 92,868,608
#define OFF_G2    92868608   // 10000*32 fp32 -> end 94,148,608
#define OFF_H3    94148608   // 10000*32 fp32 -> end 95,428,608

__device__ __forceinline__ unsigned short f2b(float f) {   // fp32 -> bf16 RNE
    unsigned int v = __float_as_uint(f);
    unsigned int r = (v + 0x7FFFu + ((v >> 16) & 1u)) >> 16;
    return (unsigned short)r;
}

__device__ __forceinline__ void gload_lds16(const void* g, void* l) {
    __builtin_amdgcn_global_load_lds(
        (const __attribute__((address_space(1))) void*)g,
        (__attribute__((address_space(3))) void*)l, 16, 0, 0);
}

// Detect int64 edge_index layout: odd int32 words of first 128 entries all zero.
__global__ void k_sniff(const int* __restrict__ edge, int* __restrict__ flag) {
    int l = threadIdx.x;   // 64 lanes
    int bad = (edge[1 + 2 * l] != 0) || (edge[129 + 2 * l] != 0);
    unsigned long long b = __ballot(bad);
    if (l == 0) *flag = (b == 0ULL) ? 1 : 0;
}

__global__ void k_count(const int* __restrict__ edge, const int* __restrict__ flag,
                        int* __restrict__ cnt) {
    int e = blockIdx.x * 256 + threadIdx.x;   // grid exactly 640000 threads
    int f = *flag;
    const int* dstp = edge + (f ? 2 * N_EDGES : N_EDGES);
    atomicAdd(&cnt[dstp[e << f]], 1);
}

__global__ void k_dinv(const int* __restrict__ cnt, float* __restrict__ dinv) {
    int i = blockIdx.x * 256 + threadIdx.x;
    if (i < N_NODES) dinv[i] = rsqrtf((float)(cnt[i] + 1));  // +1 self-loop
}

// 1024-thread 3-phase block scan: thread t owns 10 consecutive elements.
__global__ void k_scan(const int* __restrict__ cnt, int* __restrict__ rs, int* __restrict__ cur) {
    __shared__ int wsum[16];
    int t = threadIdx.x;
    int base = t * 10;
    int v[10]; int s = 0;
#pragma unroll
    for (int i = 0; i < 10; ++i) {
        int idx = base + i;
        int x = (idx < N_NODES) ? cnt[idx] : 0;
        v[i] = x; s += x;
    }
    int lane = t & 63, wid = t >> 6;
    int ps = s;
#pragma unroll
    for (int off = 1; off < 64; off <<= 1) {
        int u = __shfl_up(ps, off);
        if (lane >= off) ps += u;
    }
    if (lane == 63) wsum[wid] = ps;
    __syncthreads();
    if (wid == 0) {
        int x = (lane < 16) ? wsum[lane] : 0;
#pragma unroll
        for (int off = 1; off < 16; off <<= 1) {
            int u = __shfl_up(x, off);
            if (lane >= off) x += u;
        }
        if (lane < 16) wsum[lane] = x;   // inclusive wave sums
    }
    __syncthreads();
    int waveoff = (wid > 0) ? wsum[wid - 1] : 0;
    int run = waveoff + ps - s;          // exclusive prefix for this thread's chunk
#pragma unroll
    for (int i = 0; i < 10; ++i) {
        int idx = base + i;
        run += v[i];
        if (idx < N_NODES) { rs[idx + 1] = run; cur[idx] = run - v[i]; }
    }
    if (t == 0) rs[0] = 0;
}

__global__ void k_fill(const int* __restrict__ edge, const int* __restrict__ flag,
                       int* __restrict__ cur, int* __restrict__ csr) {
    int e = blockIdx.x * 256 + threadIdx.x;
    int f = *flag;
    const int* srcp = edge;
    const int* dstp = edge + (f ? 2 * N_EDGES : N_EDGES);
    int s = srcp[e << f];
    int d = dstp[e << f];
    int pos = atomicAdd(&cur[d], 1);
    csr[pos] = s;
}

__global__ void k_padzero(unsigned short* __restrict__ embT) {
    int i = blockIdx.x * 256 + threadIdx.x;   // 4096 total
    if (i < 256 * 16) {
        int n = i >> 4, k = i & 15;
        embT[(size_t)n * KPAD + 10000 + k] = 0;
    }
}

// emb [10000,256] fp32 -> embT [256,KPAD] bf16, LDS tile transpose
__global__ void k_transpose(const float* __restrict__ emb, unsigned short* __restrict__ embT) {
    __shared__ unsigned short t[32][65];
    int r0 = blockIdx.x * 32, c0 = blockIdx.y * 64;
    int cl = threadIdx.x & 63, rl = threadIdx.x >> 6;   // rl 0..3
    for (int i = 0; i < 8; ++i) {
        int r = r0 + rl + i * 4;
        if (r < N_NODES) t[rl + i * 4][cl] = f2b(emb[(size_t)r * 256 + c0 + cl]);
    }
    __syncthreads();
    int rr = threadIdx.x & 31, cc0 = threadIdx.x >> 5;  // cc0 0..7
    int r = r0 + rr;
    if (r < N_NODES) {
        for (int j = 0; j < 8; ++j) {
            int c = cc0 * 8 + j;
            embT[(size_t)(c0 + c) * KPAD + r] = t[rr][c];
        }
    }
}

// ---- GEMM1 (split-K): P[sp] = X[:, kslice] @ emb[kslice, :]  (fp32 partials) ----
// BM=128 BN=256 BK=32; grid (NSPLIT, 79) so blockIdx.x==sp -> each XCD owns one split
// (round-robin XCD assignment, 8 XCDs) => B-slice (~640KB) L2-resident per XCD.
// 512 threads / 8 waves; wave (wr=w>>2, wc=w&3) owns 64x64 (4x4 MFMA tiles).
// Double-buffered LDS, ONE barrier per K-step; B staged via global_load_lds (16B),
// A reg-prefetched 2 steps ahead with fp32->bf16 convert. X read exactly once (400 MB).
#define LDK 40

__global__ __launch_bounds__(512, 4) void k_gemm1(
        const float* __restrict__ X,
        const unsigned short* __restrict__ embT,
        float* __restrict__ P) {
    __shared__ __align__(16) unsigned short As[2][128 * LDK];  // 2 x 10240 B
    __shared__ __align__(16) unsigned short Bs[2][256 * 32];   // 2 x 16384 B
    const int tid = threadIdx.x;
    const int lane = tid & 63;
    const int w = tid >> 6;                 // wave 0..7
    const int wr = w >> 2, wc = w & 3;      // wave row/col in 2x4 grid
    const int sp = blockIdx.x;              // split (== XCD with round-robin)
    const int bM = blockIdx.y;              // M-block 0..78

    // K-step range: 313 = 8*39+1 -> {40,39,39,...}
    const int st0 = sp * 39 + (sp > 0 ? 1 : 0);
    const int st1 = (sp + 1) * 39 + 1;

    // A staging: thread t loads row t>>2 (0..127), 8 floats at chunk (t&3)*8
    const int ar = tid >> 2;
    const int ac8 = (tid & 3) * 8;
    int agrow = bM * 128 + ar; if (agrow > N_NODES - 1) agrow = N_NODES - 1;
    const float* gA = X + (size_t)agrow * 10000 + ac8;
    // B staging via global_load_lds: chunk index ci = s*512 + tid covers Bs linearly;
    // src row = ci>>2, k-chunk = (ci&3)*8  (512 = 0 mod 4 -> same row/chunk decomp)
    const unsigned short* gB = embT + (size_t)(tid >> 2) * KPAD + (tid & 3) * 8;

    const float4 z4 = make_float4(0.f, 0.f, 0.f, 0.f);
    float4 pa0, pa1;
    auto ldA = [&](int kk) {
        pa0 = (kk + ac8 + 4 <= 10000) ? *(const float4*)(gA + kk) : z4;
        pa1 = (kk + ac8 + 8 <= 10000) ? *(const float4*)(gA + kk + 4) : z4;
    };
    auto writeA = [&](int buf) {
        ushort4 a0, a1;
        a0.x = f2b(pa0.x); a0.y = f2b(pa0.y); a0.z = f2b(pa0.z); a0.w = f2b(pa0.w);
        a1.x = f2b(pa1.x); a1.y = f2b(pa1.y); a1.z = f2b(pa1.z); a1.w = f2b(pa1.w);
        *(ushort4*)(&As[buf][ar * LDK + ac8])     = a0;
        *(ushort4*)(&As[buf][ar * LDK + ac8 + 4]) = a1;
    };
    auto issueB = [&](int buf, int kk) {
        // issue s=0: rows 0..127, s=1: rows 128..255; wave-uniform LDS dest
        gload_lds16(gB + kk,                      &Bs[buf][(w * 64) * 8]);
        gload_lds16(gB + (size_t)128 * KPAD + kk, &Bs[buf][(512 + w * 64) * 8]);
    };

    f32x4 acc[4][4];
#pragma unroll
    for (int i = 0; i < 4; ++i)
#pragma unroll
        for (int j = 0; j < 4; ++j) acc[i][j] = (f32x4){0.f, 0.f, 0.f, 0.f};

    const int q = lane >> 4, l16 = lane & 15;

    // prologue: stage buffer 0 for st0, prefetch A regs for st0+1
    ldA(st0 * 32);
    writeA(0);
    issueB(0, st0 * 32);
    ldA((st0 + 1) * 32);

    int cur = 0;
    for (int it = st0; it < st1; ++it) {
        __syncthreads();   // drains gload_lds of buf 'cur' + makes As[cur] visible
        int nxt = cur ^ 1;
        if (it + 1 < st1) {
            writeA(nxt);                  // regs hold it+1 data
            issueB(nxt, (it + 1) * 32);   // in flight across next barrier
        }
        if (it + 2 < st1) ldA((it + 2) * 32);

        bf16x8 av[4], bv[4];
#pragma unroll
        for (int mt = 0; mt < 4; ++mt)
            av[mt] = *(const bf16x8*)(&As[cur][(wr * 64 + mt * 16 + l16) * LDK + q * 8]);
#pragma unroll
        for (int nt = 0; nt < 4; ++nt)
            bv[nt] = *(const bf16x8*)(&Bs[cur][(wc * 64 + nt * 16 + l16) * 32 + q * 8]);
#pragma unroll
        for (int mt = 0; mt < 4; ++mt)
#pragma unroll
            for (int nt = 0; nt < 4; ++nt)
                acc[mt][nt] = __builtin_amdgcn_mfma_f32_16x16x32_bf16(av[mt], bv[nt], acc[mt][nt], 0, 0, 0);
        cur = nxt;
    }

    // epilogue: C/D layout col=lane&15, row=(lane>>4)*4+reg
    float* Pp = P + (size_t)sp * N_NODES * 256;
#pragma unroll
    for (int mt = 0; mt < 4; ++mt)
#pragma unroll
        for (int nt = 0; nt < 4; ++nt) {
            int col = wc * 64 + nt * 16 + l16;
            int rbase = bM * 128 + wr * 64 + mt * 16 + q * 4;
#pragma unroll
            for (int r = 0; r < 4; ++r) {
                int row = rbase + r;
                if (row < N_NODES) Pp[(size_t)row * 256 + col] = acc[mt][nt][r];
            }
        }
}

// g1[n,f] = dinv[n] * sum_k relu(sum_sp P[sp])[n,k] * W1[k,f]  (split-K reduce fused)
__global__ void k_lin1(const float* __restrict__ P, const float* __restrict__ W1,
                       const float* __restrict__ dinv, float* __restrict__ g1) {
    __shared__ float w1s[256 * 64];   // 64 KB
    int tid = threadIdx.x;
    for (int i = tid; i < 256 * 64; i += 256) w1s[i] = W1[i];
    __syncthreads();
    int f = tid & 63, nl = tid >> 6;
    int node = blockIdx.x * 4 + nl;
    const float* h = P + (size_t)node * 256;
    const size_t STR = (size_t)N_NODES * 256;
    float acc = 0.f;
    for (int k4 = 0; k4 < 64; ++k4) {
        float sx = 0.f, sy = 0.f, sz = 0.f, sw = 0.f;
#pragma unroll
        for (int j = 0; j < NSPLIT; ++j) {
            float4 t = *(const float4*)(h + j * STR + k4 * 4);
            sx += t.x; sy += t.y; sz += t.z; sw += t.w;
        }
        const float* wp = &w1s[(k4 * 4) * 64 + f];
        acc += fmaxf(sx, 0.f) * wp[0]
             + fmaxf(sy, 0.f) * wp[64]
             + fmaxf(sz, 0.f) * wp[128]
             + fmaxf(sw, 0.f) * wp[192];
    }
    g1[(size_t)node * 64 + f] = acc * dinv[node];
}

// H2[n,f] = relu( dinv[n]*(g1[n,f] + sum_{s->n} g1[s,f]) + b1[f] )
__global__ void k_agg1(const float* __restrict__ g1, const int* __restrict__ rs,
                       const int* __restrict__ csr, const float* __restrict__ dinv,
                       const float* __restrict__ b1, float* __restrict__ H2) {
    int lane = threadIdx.x & 63;
    int node = blockIdx.x * 4 + (threadIdx.x >> 6);
    float acc = g1[(size_t)node * 64 + lane];
    int e0 = rs[node], e1 = rs[node + 1];
    for (int e = e0; e < e1; ++e) acc += g1[(size_t)csr[e] * 64 + lane];
    float o = dinv[node] * acc + b1[lane];
    H2[(size_t)node * 64 + lane] = fmaxf(o, 0.f);
}

__global__ void k_lin2(const float* __restrict__ H2, const float* __restrict__ W2,
                       const float* __restrict__ dinv, float* __restrict__ g2) {
    __shared__ float w2s[64 * 32];
    int tid = threadIdx.x;
    for (int i = tid; i < 64 * 32; i += 256) w2s[i] = W2[i];
    __syncthreads();
    int f = tid & 31, nl = tid >> 5;
    int node = blockIdx.x * 8 + nl;
    const float* h = H2 + (size_t)node * 64;
    float acc = 0.f;
#pragma unroll
    for (int k = 0; k < 64; ++k) acc += h[k] * w2s[k * 32 + f];
    g2[(size_t)node * 32 + f] = acc * dinv[node];
}

__global__ void k_agg2(const float* __restrict__ g2, const int* __restrict__ rs,
                       const int* __restrict__ csr, const float* __restrict__ dinv,
                       const float* __restrict__ b2, float* __restrict__ H3) {
    int lane = threadIdx.x & 63;
    int node = blockIdx.x * 4 + (threadIdx.x >> 6);
    int f = lane & 31, half = lane >> 5;
    int e0 = rs[node], e1 = rs[node + 1];
    float acc = 0.f;
    for (int e = e0 + half; e < e1; e += 2) acc += g2[(size_t)csr[e] * 32 + f];
    acc += __shfl_down(acc, 32);
    if (half == 0) {
        acc += g2[(size_t)node * 32 + f];
        float o = dinv[node] * acc + b2[f];
        H3[(size_t)node * 32 + f] = fmaxf(o, 0.f);
    }
}

__global__ void k_dec(const float* __restrict__ H3, const float* __restrict__ dW,
                      float* __restrict__ out) {
    __shared__ float dws[32 * 16];
    int tid = threadIdx.x;
    for (int i = tid; i < 512; i += 256) dws[i] = dW[i];
    __syncthreads();
    int j = tid & 15, nl = tid >> 4;
    int node = blockIdx.x * 16 + nl;
    const float* h = H3 + (size_t)node * 32;
    float acc = 0.f;
#pragma unroll
    for (int k = 0; k < 32; ++k) acc += h[k] * dws[k * 16 + j];
    out[(size_t)node * 16 + j] = acc;
}

extern "C" void kernel_launch(void* const* d_in, const int* in_sizes, int n_in,
                              void* d_out, int out_size, void* d_ws, size_t ws_size,
                              hipStream_t stream) {
    const float* X    = (const float*)d_in[0];
    const int*   edge = (const int*)d_in[1];
    const float* emb  = (const float*)d_in[2];
    const float* W1   = (const float*)d_in[3];
    const float* b1   = (const float*)d_in[4];
    const float* W2   = (const float*)d_in[5];
    const float* b2   = (const float*)d_in[6];
    const float* dW   = (const float*)d_in[7];
    float*       out  = (float*)d_out;

    char* ws = (char*)d_ws;
    int*            cnt  = (int*)(ws + OFF_CNT);
    int*            flag = (int*)(ws + OFF_FLAG);
    float*          dinv = (float*)(ws + OFF_DINV);
    int*            rs   = (int*)(ws + OFF_RS);
    int*            cur  = (int*)(ws + OFF_CUR);
    int*            csr  = (int*)(ws + OFF_CSR);
    unsigned short* embT = (unsigned short*)(ws + OFF_EMBT);
    float*          g1   = (float*)(ws + OFF_EMBT);  // reuse after GEMM1 consumed embT
    float*          P    = (float*)(ws + OFF_P);
    float*          H2   = (float*)(ws + OFF_H2);
    float*          g2   = (float*)(ws + OFF_G2);
    float*          H3   = (float*)(ws + OFF_H3);

    hipMemsetAsync(cnt, 0, N_NODES * sizeof(int), stream);

    k_sniff<<<1, 64, 0, stream>>>(edge, flag);
    k_count<<<N_EDGES / 256, 256, 0, stream>>>(edge, flag, cnt);
    k_dinv<<<(N_NODES + 255) / 256, 256, 0, stream>>>(cnt, dinv);
    k_scan<<<1, 1024, 0, stream>>>(cnt, rs, cur);
    k_fill<<<N_EDGES / 256, 256, 0, stream>>>(edge, flag, cur, csr);
    k_padzero<<<16, 256, 0, stream>>>(embT);
    k_transpose<<<dim3(313, 4), 256, 0, stream>>>(emb, embT);
    k_gemm1<<<dim3(NSPLIT, 79), 512, 0, stream>>>(X, embT, P);
    k_lin1<<<N_NODES / 4, 256, 0, stream>>>(P, W1, dinv, g1);
    k_agg1<<<N_NODES / 4, 256, 0, stream>>>(g1, rs, csr, dinv, b1, H2);
    k_lin2<<<N_NODES / 8, 256, 0, stream>>>(H2, W2, dinv, g2);
    k_agg2<<<N_NODES / 4, 256, 0, stream>>>(g2, rs, csr, dinv, b2, H3);
    k_dec<<<N_NODES / 16, 256, 0, stream>>>(H3, dW, out);
}

// Round 3
// 973.954 us; speedup vs baseline: 1.6364x; 1.0404x over previous
//
#include <hip/hip_runtime.h>
#include <hip/hip_bf16.h>
#include <stdint.h>

#define N_NODES 10000
#define N_EDGES 640000
#define KPAD    10016   // K=10000 padded to mult of 32 for B staging
#define NSPLIT  8       // split-K factor for GEMM1 (== 8 XCDs)

typedef __bf16 bf16x8 __attribute__((ext_vector_type(8)));
typedef float  f32x4  __attribute__((ext_vector_type(4)));

// ---- workspace layout (bytes) ----
#define OFF_CNT   0          // 10000 ints
#define OFF_FLAG  40960      // 1 int (int64-sniff flag)
#define OFF_DINV  65536      // 10000 floats
#define OFF_RS    131072     // 10001 ints (row_start)
#define OFF_CUR   196608     // 10000 ints (cursor)
#define OFF_CSR   262144     // 640000 ints -> end 2,822,144
#define OFF_EMBT  3145728    // 256*KPAD bf16 = 5,128,192 -> end 8,273,920; g1 reuses this
#define OFF_P     8388608    // NSPLIT * 10000*256 fp32 = 81,920,000 -> end 90,308,608
#define OFF_H2    90308608   // 10000*64 fp32 -> end 92,868,608
#define OFF_G2    92868608   // 10000*32 fp32 -> end 94,148,608

__device__ __forceinline__ unsigned short f2b(float f) {   // fp32 -> bf16 RNE
    unsigned int v = __float_as_uint(f);
    unsigned int r = (v + 0x7FFFu + ((v >> 16) & 1u)) >> 16;
    return (unsigned short)r;
}

__device__ __forceinline__ void gload_lds16(const void* g, void* l) {
    __builtin_amdgcn_global_load_lds(
        (const __attribute__((address_space(1))) void*)g,
        (__attribute__((address_space(3))) void*)l, 16, 0, 0);
}

// Detect int64 edge_index layout: odd int32 words of first 128 entries all zero.
__global__ void k_sniff(const int* __restrict__ edge, int* __restrict__ flag) {
    int l = threadIdx.x;   // 64 lanes
    int bad = (edge[1 + 2 * l] != 0) || (edge[129 + 2 * l] != 0);
    unsigned long long b = __ballot(bad);
    if (l == 0) *flag = (b == 0ULL) ? 1 : 0;
}

__global__ void k_count(const int* __restrict__ edge, const int* __restrict__ flag,
                        int* __restrict__ cnt) {
    int e = blockIdx.x * 256 + threadIdx.x;   // grid exactly 640000 threads
    int f = *flag;
    const int* dstp = edge + (f ? 2 * N_EDGES : N_EDGES);
    atomicAdd(&cnt[dstp[e << f]], 1);
}

// 1024-thread 3-phase block scan (thread t owns 10 elements) + fused dinv + embT pad.
__global__ void k_scan(const int* __restrict__ cnt, int* __restrict__ rs, int* __restrict__ cur,
                       float* __restrict__ dinv, unsigned short* __restrict__ embT) {
    __shared__ int wsum[16];
    int t = threadIdx.x;
    // fused padzero: cols 10000..10015 of all 256 embT rows
    for (int i = t; i < 256 * 16; i += 1024) {
        int n = i >> 4, k = i & 15;
        embT[(size_t)n * KPAD + 10000 + k] = 0;
    }
    int base = t * 10;
    int v[10]; int s = 0;
#pragma unroll
    for (int i = 0; i < 10; ++i) {
        int idx = base + i;
        int x = (idx < N_NODES) ? cnt[idx] : 0;
        v[i] = x; s += x;
        if (idx < N_NODES) dinv[idx] = rsqrtf((float)(x + 1));  // +1 self-loop
    }
    int lane = t & 63, wid = t >> 6;
    int ps = s;
#pragma unroll
    for (int off = 1; off < 64; off <<= 1) {
        int u = __shfl_up(ps, off);
        if (lane >= off) ps += u;
    }
    if (lane == 63) wsum[wid] = ps;
    __syncthreads();
    if (wid == 0) {
        int x = (lane < 16) ? wsum[lane] : 0;
#pragma unroll
        for (int off = 1; off < 16; off <<= 1) {
            int u = __shfl_up(x, off);
            if (lane >= off) x += u;
        }
        if (lane < 16) wsum[lane] = x;   // inclusive wave sums
    }
    __syncthreads();
    int waveoff = (wid > 0) ? wsum[wid - 1] : 0;
    int run = waveoff + ps - s;          // exclusive prefix for this thread's chunk
#pragma unroll
    for (int i = 0; i < 10; ++i) {
        int idx = base + i;
        run += v[i];
        if (idx < N_NODES) { rs[idx + 1] = run; cur[idx] = run - v[i]; }
    }
    if (t == 0) rs[0] = 0;
}

__global__ void k_fill(const int* __restrict__ edge, const int* __restrict__ flag,
                       int* __restrict__ cur, int* __restrict__ csr) {
    int e = blockIdx.x * 256 + threadIdx.x;
    int f = *flag;
    const int* srcp = edge;
    const int* dstp = edge + (f ? 2 * N_EDGES : N_EDGES);
    int s = srcp[e << f];
    int d = dstp[e << f];
    int pos = atomicAdd(&cur[d], 1);
    csr[pos] = s;
}

// emb [10000,256] fp32 -> embT [256,KPAD] bf16; 64x64 tiles so embT stores are
// full 128-B contiguous lines (64 lanes x 2B) -- avoids write-allocate waste.
__global__ void k_transpose(const float* __restrict__ emb, unsigned short* __restrict__ embT) {
    __shared__ unsigned short t[64][65];
    int r0 = blockIdx.x * 64, c0 = blockIdx.y * 64;
    int tid = threadIdx.x;
    int cl = tid & 63, rq = tid >> 6;       // rq 0..3
#pragma unroll
    for (int i = 0; i < 16; ++i) {
        int rr = rq + i * 4;                // 0..63
        int r = r0 + rr;
        if (r < N_NODES) t[rr][cl] = f2b(emb[(size_t)r * 256 + c0 + cl]);
    }
    __syncthreads();
    int rr = tid & 63, cq = tid >> 6;       // cq 0..3
    int r = r0 + rr;
    if (r < N_NODES) {
#pragma unroll
        for (int j = 0; j < 16; ++j) {
            int c = cq * 16 + j;
            embT[(size_t)(c0 + c) * KPAD + r] = t[rr][c];
        }
    }
}

// ---- GEMM1 (split-K): P[sp] = X[:, kslice] @ emb[kslice, :]  (fp32 partials) ----
// BM=128 BN=256 BK=32; grid (NSPLIT, 79): blockIdx.x==sp -> round-robin XCD =>
// each XCD owns one K-split, B-slice L2-resident. 512 thr / 8 waves, 64x64/wave.
// Double-buffered LDS, ONE barrier per K-step. A global-prefetch at 64-col
// granularity (64 B contiguous per thread -> 256 B per row per epoch) staged in
// alternating 32-col halves; B via global_load_lds (16B). X read once (400 MB).
#define LDK 40

__global__ __launch_bounds__(512, 4) void k_gemm1(
        const float* __restrict__ X,
        const unsigned short* __restrict__ embT,
        float* __restrict__ P) {
    __shared__ __align__(16) unsigned short As[2][128 * LDK];  // 2 x 10240 B
    __shared__ __align__(16) unsigned short Bs[2][256 * 32];   // 2 x 16384 B
    const int tid = threadIdx.x;
    const int lane = tid & 63;
    const int w = tid >> 6;                 // wave 0..7
    const int wr = w >> 2, wc = w & 3;      // wave row/col in 2x4 grid
    const int sp = blockIdx.x;              // split (== XCD with round-robin)
    const int bM = blockIdx.y;              // M-block 0..78

    // K-step range: 313 = 8*39+1 -> {40,39,39,...}
    const int st0 = sp * 39 + (sp > 0 ? 1 : 0);
    const int nsteps = ((sp + 1) * 39 + 1) - st0;

    // A: thread t covers row t>>2, 16 consecutive floats at col (t&3)*16 of a
    // 64-col (2-step) pair. Per-thread 64 B contiguous global reads.
    const int ar = tid >> 2;
    const int c16 = (tid & 3) * 16;
    int agrow = bM * 128 + ar; if (agrow > N_NODES - 1) agrow = N_NODES - 1;
    const float* gA = X + (size_t)agrow * 10000 + c16;
    // B staging via global_load_lds: chunk ci = s*512 + tid -> row ci>>2, col (ci&3)*8
    const unsigned short* gB = embT + (size_t)(tid >> 2) * KPAD + (tid & 3) * 8;

    const float4 z4 = make_float4(0.f, 0.f, 0.f, 0.f);
    float4 pa[4];
    auto ldA2 = [&](int ub) {               // ub = even local step; loads 64 cols
        const int kb = (st0 + ub) * 32;
#pragma unroll
        for (int j = 0; j < 4; ++j)
            pa[j] = (kb + c16 + j * 4 + 4 <= 10000) ? *(const float4*)(gA + kb + j * 4) : z4;
    };
    auto writeA = [&](int buf, int half) {  // stage 32-col half from reg pair
        if (((tid >> 1) & 1) == half) {
            unsigned int q[8];
#pragma unroll
            for (int j = 0; j < 4; ++j) {
                q[2 * j]     = (unsigned int)f2b(pa[j].x) | ((unsigned int)f2b(pa[j].y) << 16);
                q[2 * j + 1] = (unsigned int)f2b(pa[j].z) | ((unsigned int)f2b(pa[j].w) << 16);
            }
            unsigned short* dst = &As[buf][ar * LDK + (c16 & 31)];
            *(uint4*)(dst)     = make_uint4(q[0], q[1], q[2], q[3]);
            *(uint4*)(dst + 8) = make_uint4(q[4], q[5], q[6], q[7]);
        }
    };
    auto issueB = [&](int buf, int it) {
        const int kk = it * 32;
        gload_lds16(gB + kk,                      &Bs[buf][(w * 64) * 8]);
        gload_lds16(gB + (size_t)128 * KPAD + kk, &Bs[buf][(512 + w * 64) * 8]);
    };

    f32x4 acc[4][4];
#pragma unroll
    for (int i = 0; i < 4; ++i)
#pragma unroll
        for (int j = 0; j < 4; ++j) acc[i][j] = (f32x4){0.f, 0.f, 0.f, 0.f};

    const int q = lane >> 4, l16 = lane & 15;

    // prologue: load pair {0,1}, stage buf0 with local step 0
    ldA2(0);
    writeA(0, 0);
    issueB(0, st0);

    int cur = 0;
    for (int u = 0; u < nsteps; ++u) {
        __syncthreads();   // drains gload_lds + A-pair loads; As/Bs[cur] ready
        int nxt = cur ^ 1;
        if (u + 1 < nsteps) {
            writeA(nxt, (u + 1) & 1);          // consumes reg pair (u+1)&~1
            issueB(nxt, st0 + u + 1);
        }
        if (((u & 1) == 0) && (u + 2 < nsteps)) ldA2(u + 2);  // pair fully consumed

        bf16x8 av[4], bv[4];
#pragma unroll
        for (int mt = 0; mt < 4; ++mt)
            av[mt] = *(const bf16x8*)(&As[cur][(wr * 64 + mt * 16 + l16) * LDK + q * 8]);
#pragma unroll
        for (int nt = 0; nt < 4; ++nt)
            bv[nt] = *(const bf16x8*)(&Bs[cur][(wc * 64 + nt * 16 + l16) * 32 + q * 8]);
#pragma unroll
        for (int mt = 0; mt < 4; ++mt)
#pragma unroll
            for (int nt = 0; nt < 4; ++nt)
                acc[mt][nt] = __builtin_amdgcn_mfma_f32_16x16x32_bf16(av[mt], bv[nt], acc[mt][nt], 0, 0, 0);
        cur = nxt;
    }

    // epilogue: C/D layout col=lane&15, row=(lane>>4)*4+reg
    float* Pp = P + (size_t)sp * N_NODES * 256;
#pragma unroll
    for (int mt = 0; mt < 4; ++mt)
#pragma unroll
        for (int nt = 0; nt < 4; ++nt) {
            int col = wc * 64 + nt * 16 + l16;
            int rbase = bM * 128 + wr * 64 + mt * 16 + q * 4;
#pragma unroll
            for (int r = 0; r < 4; ++r) {
                int row = rbase + r;
                if (row < N_NODES) Pp[(size_t)row * 256 + col] = acc[mt][nt][r];
            }
        }
}

// g1[n,f] = dinv[n] * sum_k relu(sum_sp P[sp])[n,k] * W1[k,f]  (split-K reduce fused)
__global__ void k_lin1(const float* __restrict__ P, const float* __restrict__ W1,
                       const float* __restrict__ dinv, float* __restrict__ g1) {
    __shared__ float w1s[256 * 64];   // 64 KB
    int tid = threadIdx.x;
    for (int i = tid; i < 256 * 64; i += 256) w1s[i] = W1[i];
    __syncthreads();
    int f = tid & 63, nl = tid >> 6;
    int node = blockIdx.x * 4 + nl;
    const float* h = P + (size_t)node * 256;
    const size_t STR = (size_t)N_NODES * 256;
    float acc = 0.f;
    for (int k4 = 0; k4 < 64; ++k4) {
        float sx = 0.f, sy = 0.f, sz = 0.f, sw = 0.f;
#pragma unroll
        for (int j = 0; j < NSPLIT; ++j) {
            float4 t = *(const float4*)(h + j * STR + k4 * 4);
            sx += t.x; sy += t.y; sz += t.z; sw += t.w;
        }
        const float* wp = &w1s[(k4 * 4) * 64 + f];
        acc += fmaxf(sx, 0.f) * wp[0]
             + fmaxf(sy, 0.f) * wp[64]
             + fmaxf(sz, 0.f) * wp[128]
             + fmaxf(sw, 0.f) * wp[192];
    }
    g1[(size_t)node * 64 + f] = acc * dinv[node];
}

// H2[n,f] = relu( dinv[n]*(g1[n,f] + sum_{s->n} g1[s,f]) + b1[f] )
// 4-deep gather pipeline: 4 independent row loads in flight per wave.
__global__ void k_agg1(const float* __restrict__ g1, const int* __restrict__ rs,
                       const int* __restrict__ csr, const float* __restrict__ dinv,
                       const float* __restrict__ b1, float* __restrict__ H2) {
    int lane = threadIdx.x & 63;
    int node = blockIdx.x * 4 + (threadIdx.x >> 6);
    float acc = g1[(size_t)node * 64 + lane];
    int e0 = rs[node], e1 = rs[node + 1];
    int e = e0;
    for (; e + 4 <= e1; e += 4) {
        int s0 = csr[e], s1 = csr[e + 1], s2 = csr[e + 2], s3 = csr[e + 3];
        float v0 = g1[(size_t)s0 * 64 + lane];
        float v1 = g1[(size_t)s1 * 64 + lane];
        float v2 = g1[(size_t)s2 * 64 + lane];
        float v3 = g1[(size_t)s3 * 64 + lane];
        acc += v0 + v1 + v2 + v3;
    }
    for (; e < e1; ++e) acc += g1[(size_t)csr[e] * 64 + lane];
    float o = dinv[node] * acc + b1[lane];
    H2[(size_t)node * 64 + lane] = fmaxf(o, 0.f);
}

__global__ void k_lin2(const float* __restrict__ H2, const float* __restrict__ W2,
                       const float* __restrict__ dinv, float* __restrict__ g2) {
    __shared__ float w2s[64 * 32];
    int tid = threadIdx.x;
    for (int i = tid; i < 64 * 32; i += 256) w2s[i] = W2[i];
    __syncthreads();
    int f = tid & 31, nl = tid >> 5;
    int node = blockIdx.x * 8 + nl;
    const float* h = H2 + (size_t)node * 64;
    float acc = 0.f;
#pragma unroll
    for (int k = 0; k < 64; ++k) acc += h[k] * w2s[k * 32 + f];
    g2[(size_t)node * 32 + f] = acc * dinv[node];
}

// H3 = relu(dinv*(g2 self+neigh)+b2) computed in-block, then fused decoder:
// out[n,0:16] = H3row @ dW. Saves the H3 global roundtrip + a launch.
__global__ void k_agg2d(const float* __restrict__ g2, const int* __restrict__ rs,
                        const int* __restrict__ csr, const float* __restrict__ dinv,
                        const float* __restrict__ b2, const float* __restrict__ dW,
                        float* __restrict__ out) {
    __shared__ float dws[32 * 16];
    __shared__ float sh3[4][32];
    int tid = threadIdx.x;
    for (int i = tid; i < 512; i += 256) dws[i] = dW[i];
    int lane = tid & 63;
    int nl = tid >> 6;
    int node = blockIdx.x * 4 + nl;
    int f = lane & 31, half = lane >> 5;
    int e0 = rs[node], e1 = rs[node + 1];
    float acc = 0.f;
    int e = e0 + half;
    for (; e + 6 < e1; e += 8) {
        int s0 = csr[e], s1 = csr[e + 2], s2 = csr[e + 4], s3 = csr[e + 6];
        float v0 = g2[(size_t)s0 * 32 + f];
        float v1 = g2[(size_t)s1 * 32 + f];
        float v2 = g2[(size_t)s2 * 32 + f];
        float v3 = g2[(size_t)s3 * 32 + f];
        acc += v0 + v1 + v2 + v3;
    }
    for (; e < e1; e += 2) acc += g2[(size_t)csr[e] * 32 + f];
    acc += __shfl_down(acc, 32);
    if (half == 0) {
        acc += g2[(size_t)node * 32 + f];
        sh3[nl][f] = fmaxf(dinv[node] * acc + b2[f], 0.f);
    }
    __syncthreads();
    if (tid < 64) {
        int j = tid & 15, n2 = tid >> 4;
        float a = 0.f;
#pragma unroll
        for (int k = 0; k < 32; ++k) a += sh3[n2][k] * dws[k * 16 + j];
        out[(size_t)(blockIdx.x * 4 + n2) * 16 + j] = a;
    }
}

extern "C" void kernel_launch(void* const* d_in, const int* in_sizes, int n_in,
                              void* d_out, int out_size, void* d_ws, size_t ws_size,
                              hipStream_t stream) {
    const float* X    = (const float*)d_in[0];
    const int*   edge = (const int*)d_in[1];
    const float* emb  = (const float*)d_in[2];
    const float* W1   = (const float*)d_in[3];
    const float* b1   = (const float*)d_in[4];
    const float* W2   = (const float*)d_in[5];
    const float* b2   = (const float*)d_in[6];
    const float* dW   = (const float*)d_in[7];
    float*       out  = (float*)d_out;

    char* ws = (char*)d_ws;
    int*            cnt  = (int*)(ws + OFF_CNT);
    int*            flag = (int*)(ws + OFF_FLAG);
    float*          dinv = (float*)(ws + OFF_DINV);
    int*            rs   = (int*)(ws + OFF_RS);
    int*            cur  = (int*)(ws + OFF_CUR);
    int*            csr  = (int*)(ws + OFF_CSR);
    unsigned short* embT = (unsigned short*)(ws + OFF_EMBT);
    float*          g1   = (float*)(ws + OFF_EMBT);  // reuse after GEMM1 consumed embT
    float*          P    = (float*)(ws + OFF_P);
    float*          H2   = (float*)(ws + OFF_H2);
    float*          g2   = (float*)(ws + OFF_G2);

    hipMemsetAsync(cnt, 0, N_NODES * sizeof(int), stream);

    k_sniff<<<1, 64, 0, stream>>>(edge, flag);
    k_count<<<N_EDGES / 256, 256, 0, stream>>>(edge, flag, cnt);
    k_scan<<<1, 1024, 0, stream>>>(cnt, rs, cur, dinv, embT);
    k_fill<<<N_EDGES / 256, 256, 0, stream>>>(edge, flag, cur, csr);
    k_transpose<<<dim3(157, 4), 256, 0, stream>>>(emb, embT);
    k_gemm1<<<dim3(NSPLIT, 79), 512, 0, stream>>>(X, embT, P);
    k_lin1<<<N_NODES / 4, 256, 0, stream>>>(P, W1, dinv, g1);
    k_agg1<<<N_NODES / 4, 256, 0, stream>>>(g1, rs, csr, dinv, b1, H2);
    k_lin2<<<N_NODES / 8, 256, 0, stream>>>(H2, W2, dinv, g2);
    k_agg2d<<<N_NODES / 4, 256, 0, stream>>>(g2, rs, csr, dinv, b2, dW, out);
}

// Round 4
// 920.130 us; speedup vs baseline: 1.7321x; 1.0585x over previous
//
#include <hip/hip_runtime.h>
#include <hip/hip_bf16.h>
#include <stdint.h>

#define N_NODES 10000
#define N_EDGES 640000
#define KPAD    10016   // K=10000 padded to mult of 32 for B staging
#define NSPLIT  8       // split-K factor for GEMM1 (== 8 XCDs)

typedef __bf16 bf16x8 __attribute__((ext_vector_type(8)));
typedef float  f32x4  __attribute__((ext_vector_type(4)));

// ---- workspace layout (bytes) ----
#define OFF_CNT   0          // 10000 ints
#define OFF_FLAG  40960      // 1 int (int64-sniff flag)
#define OFF_DINV  65536      // 10000 floats
#define OFF_RS    131072     // 10001 ints (row_start)
#define OFF_CUR   196608     // 10000 ints (cursor)
#define OFF_CSR   262144     // 640000 ints -> end 2,822,144
#define OFF_EMBT  3145728    // 256*KPAD bf16 = 5,128,192 -> end 8,273,920; g1 reuses this
#define OFF_P     8388608    // NSPLIT * 10000*256 fp32 = 81,920,000 -> end 90,308,608
#define OFF_H2    90308608   // 10000*64 fp32 -> end 92,868,608
#define OFF_G2    92868608   // 10000*32 fp32 -> end 94,148,608

__device__ __forceinline__ unsigned short f2b(float f) {   // fp32 -> bf16 RNE
    unsigned int v = __float_as_uint(f);
    unsigned int r = (v + 0x7FFFu + ((v >> 16) & 1u)) >> 16;
    return (unsigned short)r;
}

__device__ __forceinline__ void gload_lds16(const void* g, void* l) {
    __builtin_amdgcn_global_load_lds(
        (const __attribute__((address_space(1))) void*)g,
        (__attribute__((address_space(3))) void*)l, 16, 0, 0);
}

// Detect int64 edge_index layout: odd int32 words of first 128 entries all zero.
__global__ void k_sniff(const int* __restrict__ edge, int* __restrict__ flag) {
    int l = threadIdx.x;   // 64 lanes
    int bad = (edge[1 + 2 * l] != 0) || (edge[129 + 2 * l] != 0);
    unsigned long long b = __ballot(bad);
    if (l == 0) *flag = (b == 0ULL) ? 1 : 0;
}

__global__ void k_count(const int* __restrict__ edge, const int* __restrict__ flag,
                        int* __restrict__ cnt) {
    int e = blockIdx.x * 256 + threadIdx.x;   // grid exactly 640000 threads
    int f = *flag;
    const int* dstp = edge + (f ? 2 * N_EDGES : N_EDGES);
    atomicAdd(&cnt[dstp[e << f]], 1);
}

// 1024-thread 3-phase block scan (thread t owns 10 elements) + fused dinv + embT pad.
__global__ void k_scan(const int* __restrict__ cnt, int* __restrict__ rs, int* __restrict__ cur,
                       float* __restrict__ dinv, unsigned short* __restrict__ embT) {
    __shared__ int wsum[16];
    int t = threadIdx.x;
    // fused padzero: cols 10000..10015 of all 256 embT rows
    for (int i = t; i < 256 * 16; i += 1024) {
        int n = i >> 4, k = i & 15;
        embT[(size_t)n * KPAD + 10000 + k] = 0;
    }
    int base = t * 10;
    int v[10]; int s = 0;
#pragma unroll
    for (int i = 0; i < 10; ++i) {
        int idx = base + i;
        int x = (idx < N_NODES) ? cnt[idx] : 0;
        v[i] = x; s += x;
        if (idx < N_NODES) dinv[idx] = rsqrtf((float)(x + 1));  // +1 self-loop
    }
    int lane = t & 63, wid = t >> 6;
    int ps = s;
#pragma unroll
    for (int off = 1; off < 64; off <<= 1) {
        int u = __shfl_up(ps, off);
        if (lane >= off) ps += u;
    }
    if (lane == 63) wsum[wid] = ps;
    __syncthreads();
    if (wid == 0) {
        int x = (lane < 16) ? wsum[lane] : 0;
#pragma unroll
        for (int off = 1; off < 16; off <<= 1) {
            int u = __shfl_up(x, off);
            if (lane >= off) x += u;
        }
        if (lane < 16) wsum[lane] = x;   // inclusive wave sums
    }
    __syncthreads();
    int waveoff = (wid > 0) ? wsum[wid - 1] : 0;
    int run = waveoff + ps - s;          // exclusive prefix for this thread's chunk
#pragma unroll
    for (int i = 0; i < 10; ++i) {
        int idx = base + i;
        run += v[i];
        if (idx < N_NODES) { rs[idx + 1] = run; cur[idx] = run - v[i]; }
    }
    if (t == 0) rs[0] = 0;
}

__global__ void k_fill(const int* __restrict__ edge, const int* __restrict__ flag,
                       int* __restrict__ cur, int* __restrict__ csr) {
    int e = blockIdx.x * 256 + threadIdx.x;
    int f = *flag;
    const int* srcp = edge;
    const int* dstp = edge + (f ? 2 * N_EDGES : N_EDGES);
    int s = srcp[e << f];
    int d = dstp[e << f];
    int pos = atomicAdd(&cur[d], 1);
    csr[pos] = s;
}

// emb [10000,256] fp32 -> embT [256,KPAD] bf16; 64x64 tiles so embT stores are
// full 128-B contiguous lines (64 lanes x 2B).
__global__ void k_transpose(const float* __restrict__ emb, unsigned short* __restrict__ embT) {
    __shared__ unsigned short t[64][65];
    int r0 = blockIdx.x * 64, c0 = blockIdx.y * 64;
    int tid = threadIdx.x;
    int cl = tid & 63, rq = tid >> 6;       // rq 0..3
#pragma unroll
    for (int i = 0; i < 16; ++i) {
        int rr = rq + i * 4;                // 0..63
        int r = r0 + rr;
        if (r < N_NODES) t[rr][cl] = f2b(emb[(size_t)r * 256 + c0 + cl]);
    }
    __syncthreads();
    int rr = tid & 63, cq = tid >> 6;       // cq 0..3
    int r = r0 + rr;
    if (r < N_NODES) {
#pragma unroll
        for (int j = 0; j < 16; ++j) {
            int c = cq * 16 + j;
            embT[(size_t)(c0 + c) * KPAD + r] = t[rr][c];
        }
    }
}

// ---- GEMM1 (split-K): P[sp] = X[:, kslice] @ emb[kslice, :]  (fp32 partials) ----
// BM=64 BN=256 BK=32; grid (NSPLIT, 157): linear id = sp + 8*bM -> XCD = sp
// (round-robin) => per-XCD B-slice L2-resident. 256 thr / 4 waves, 64x64/wave.
// 1256 blocks (~5/CU work, 4 resident by 40KB LDS) -> latency hidden by block TLP.
// LDS layout CHUNKED [k-chunk q][row]*16B: all ds accesses are 16 consecutive
// 16-B slots per 16-lane group -> bank-conflict-free. gload_lds dest stays
// linear; per-lane GLOBAL source is remapped instead (both-sides rule).
__global__ __launch_bounds__(256, 4) void k_gemm1(
        const float* __restrict__ X,
        const unsigned short* __restrict__ embT,
        float* __restrict__ P) {
    __shared__ __align__(16) unsigned short As[2][4 * 64 * 8];    // 2 x 4 KB
    __shared__ __align__(16) unsigned short Bs[2][4 * 256 * 8];   // 2 x 16 KB
    const int tid = threadIdx.x;
    const int lane = tid & 63;
    const int wc = tid >> 6;                // wave 0..3 -> 64-col slice
    const int sp = blockIdx.x;              // split (== XCD with round-robin)
    const int bM = blockIdx.y;              // M-block 0..156

    // K-step range: 313 = 8*39+1 -> {40,39,...,39}
    const int st0 = sp * 39 + (sp > 0 ? 1 : 0);
    const int nsteps = ((sp + 1) * 39 + 1) - st0;

    // A staging: thread -> row ar=tid>>2 (0..63), k-chunk ac=tid&3 (8 fp32 = 32B)
    const int ar = tid >> 2, ac = tid & 3;
    int agrow = bM * 64 + ar; if (agrow > N_NODES - 1) agrow = N_NODES - 1;
    const float* gA = X + (size_t)agrow * 10000 + ac * 8;
    // B staging: issue s stages k-chunk s of all 256 rows; lane covers row tid
    const unsigned short* gB = embT + (size_t)tid * KPAD;

    const float4 z4 = make_float4(0.f, 0.f, 0.f, 0.f);
    float4 pa0, pa1;
    auto ldA = [&](int it) {
        const int kb = it * 32 + ac * 8;
        pa0 = (kb + 4 <= 10000) ? *(const float4*)(gA + it * 32) : z4;
        pa1 = (kb + 8 <= 10000) ? *(const float4*)(gA + it * 32 + 4) : z4;
    };
    auto writeA = [&](int buf) {
        uint4 qv;
        qv.x = (unsigned)f2b(pa0.x) | ((unsigned)f2b(pa0.y) << 16);
        qv.y = (unsigned)f2b(pa0.z) | ((unsigned)f2b(pa0.w) << 16);
        qv.z = (unsigned)f2b(pa1.x) | ((unsigned)f2b(pa1.y) << 16);
        qv.w = (unsigned)f2b(pa1.z) | ((unsigned)f2b(pa1.w) << 16);
        *(uint4*)(&As[buf][(ac * 64 + ar) * 8]) = qv;   // slot = chunk*64 + row
    };
    auto issueB = [&](int buf, int it) {
        const int kk = it * 32;
#pragma unroll
        for (int s = 0; s < 4; ++s)   // dest slot = s*256 + tid (wave-uniform base)
            gload_lds16(gB + kk + s * 8, &Bs[buf][(s * 256 + wc * 64) * 8]);
    };

    f32x4 acc[4][4];
#pragma unroll
    for (int i = 0; i < 4; ++i)
#pragma unroll
        for (int j = 0; j < 4; ++j) acc[i][j] = (f32x4){0.f, 0.f, 0.f, 0.f};

    const int q = lane >> 4, l16 = lane & 15;

    // prologue
    ldA(st0);
    writeA(0);
    issueB(0, st0);
    ldA(st0 + 1);   // nsteps >= 39 always

    int cur = 0;
    for (int u = 0; u < nsteps; ++u) {
        __syncthreads();   // drains gload_lds + A reg loads; As/Bs[cur] ready
        if (u + 1 < nsteps) {
            writeA(cur ^ 1);
            issueB(cur ^ 1, st0 + u + 1);
        }
        if (u + 2 < nsteps) ldA(st0 + u + 2);

        bf16x8 av[4], bv[4];
#pragma unroll
        for (int mt = 0; mt < 4; ++mt)
            av[mt] = *(const bf16x8*)(&As[cur][(q * 64 + mt * 16 + l16) * 8]);
#pragma unroll
        for (int nt = 0; nt < 4; ++nt)
            bv[nt] = *(const bf16x8*)(&Bs[cur][(q * 256 + wc * 64 + nt * 16 + l16) * 8]);
#pragma unroll
        for (int mt = 0; mt < 4; ++mt)
#pragma unroll
            for (int nt = 0; nt < 4; ++nt)
                acc[mt][nt] = __builtin_amdgcn_mfma_f32_16x16x32_bf16(av[mt], bv[nt], acc[mt][nt], 0, 0, 0);
        cur ^= 1;
    }

    // epilogue: C/D layout col=lane&15, row=(lane>>4)*4+reg
    float* Pp = P + (size_t)sp * N_NODES * 256;
#pragma unroll
    for (int mt = 0; mt < 4; ++mt)
#pragma unroll
        for (int nt = 0; nt < 4; ++nt) {
            int col = wc * 64 + nt * 16 + l16;
            int rbase = bM * 64 + mt * 16 + q * 4;
#pragma unroll
            for (int r = 0; r < 4; ++r) {
                int row = rbase + r;
                if (row < N_NODES) Pp[(size_t)row * 256 + col] = acc[mt][nt][r];
            }
        }
}

// g1[n,f] = dinv[n] * sum_k relu(sum_sp P[sp])[n,k] * W1[k,f]
// 16 nodes/block; phase 1: coalesced cooperative split-reduce into LDS (1-KB
// contiguous row reads); phase 2: GEMV from LDS (broadcast reads, conflict-free).
__global__ __launch_bounds__(256) void k_lin1(const float* __restrict__ P,
        const float* __restrict__ W1, const float* __restrict__ dinv,
        float* __restrict__ g1) {
    __shared__ float w1s[256 * 64];   // 64 KB
    __shared__ float hs[16][256];     // 16 KB
    int tid = threadIdx.x;
    for (int i = tid; i < 256 * 64; i += 256) w1s[i] = W1[i];
    const int nbase = blockIdx.x * 16;
    const size_t STR = (size_t)N_NODES * 256;
    const int k4 = tid & 63, nl = tid >> 6;   // wave nl
#pragma unroll
    for (int i = 0; i < 4; ++i) {
        int n = nl * 4 + i;
        const float* p = P + (size_t)(nbase + n) * 256 + k4 * 4;
        float4 a = make_float4(0.f, 0.f, 0.f, 0.f);
#pragma unroll
        for (int j = 0; j < NSPLIT; ++j) {
            float4 t = *(const float4*)(p + (size_t)j * STR);
            a.x += t.x; a.y += t.y; a.z += t.z; a.w += t.w;
        }
        float4 rl = make_float4(fmaxf(a.x, 0.f), fmaxf(a.y, 0.f),
                                fmaxf(a.z, 0.f), fmaxf(a.w, 0.f));
        *(float4*)(&hs[n][k4 * 4]) = rl;
    }
    __syncthreads();
    const int f = tid & 63;
#pragma unroll
    for (int i = 0; i < 4; ++i) {
        int n = nl * 4 + i;
        float acc = 0.f;
#pragma unroll 8
        for (int kq = 0; kq < 64; ++kq) {
            float4 h = *(const float4*)(&hs[n][kq * 4]);
            const float* wp = &w1s[kq * 4 * 64 + f];
            acc += h.x * wp[0] + h.y * wp[64] + h.z * wp[128] + h.w * wp[192];
        }
        int gn = nbase + n;
        g1[(size_t)gn * 64 + f] = acc * dinv[gn];
    }
}

// H2[n,f] = relu( dinv[n]*(g1[n,f] + sum_{s->n} g1[s,f]) + b1[f] )
// 4-deep gather pipeline: 4 independent row loads in flight per wave.
__global__ void k_agg1(const float* __restrict__ g1, const int* __restrict__ rs,
                       const int* __restrict__ csr, const float* __restrict__ dinv,
                       const float* __restrict__ b1, float* __restrict__ H2) {
    int lane = threadIdx.x & 63;
    int node = blockIdx.x * 4 + (threadIdx.x >> 6);
    float acc = g1[(size_t)node * 64 + lane];
    int e0 = rs[node], e1 = rs[node + 1];
    int e = e0;
    for (; e + 4 <= e1; e += 4) {
        int s0 = csr[e], s1 = csr[e + 1], s2 = csr[e + 2], s3 = csr[e + 3];
        float v0 = g1[(size_t)s0 * 64 + lane];
        float v1 = g1[(size_t)s1 * 64 + lane];
        float v2 = g1[(size_t)s2 * 64 + lane];
        float v3 = g1[(size_t)s3 * 64 + lane];
        acc += v0 + v1 + v2 + v3;
    }
    for (; e < e1; ++e) acc += g1[(size_t)csr[e] * 64 + lane];
    float o = dinv[node] * acc + b1[lane];
    H2[(size_t)node * 64 + lane] = fmaxf(o, 0.f);
}

__global__ void k_lin2(const float* __restrict__ H2, const float* __restrict__ W2,
                       const float* __restrict__ dinv, float* __restrict__ g2) {
    __shared__ float w2s[64 * 32];
    int tid = threadIdx.x;
    for (int i = tid; i < 64 * 32; i += 256) w2s[i] = W2[i];
    __syncthreads();
    int f = tid & 31, nl = tid >> 5;
    int node = blockIdx.x * 8 + nl;
    const float* h = H2 + (size_t)node * 64;
    float acc = 0.f;
#pragma unroll
    for (int k = 0; k < 64; ++k) acc += h[k] * w2s[k * 32 + f];
    g2[(size_t)node * 32 + f] = acc * dinv[node];
}

// H3 = relu(dinv*(g2 self+neigh)+b2) in-block, then fused decoder out = H3 @ dW.
__global__ void k_agg2d(const float* __restrict__ g2, const int* __restrict__ rs,
                        const int* __restrict__ csr, const float* __restrict__ dinv,
                        const float* __restrict__ b2, const float* __restrict__ dW,
                        float* __restrict__ out) {
    __shared__ float dws[32 * 16];
    __shared__ float sh3[4][32];
    int tid = threadIdx.x;
    for (int i = tid; i < 512; i += 256) dws[i] = dW[i];
    int lane = tid & 63;
    int nl = tid >> 6;
    int node = blockIdx.x * 4 + nl;
    int f = lane & 31, half = lane >> 5;
    int e0 = rs[node], e1 = rs[node + 1];
    float acc = 0.f;
    int e = e0 + half;
    for (; e + 6 < e1; e += 8) {
        int s0 = csr[e], s1 = csr[e + 2], s2 = csr[e + 4], s3 = csr[e + 6];
        float v0 = g2[(size_t)s0 * 32 + f];
        float v1 = g2[(size_t)s1 * 32 + f];
        float v2 = g2[(size_t)s2 * 32 + f];
        float v3 = g2[(size_t)s3 * 32 + f];
        acc += v0 + v1 + v2 + v3;
    }
    for (; e < e1; e += 2) acc += g2[(size_t)csr[e] * 32 + f];
    acc += __shfl_down(acc, 32);
    if (half == 0) {
        acc += g2[(size_t)node * 32 + f];
        sh3[nl][f] = fmaxf(dinv[node] * acc + b2[f], 0.f);
    }
    __syncthreads();
    if (tid < 64) {
        int j = tid & 15, n2 = tid >> 4;
        float a = 0.f;
#pragma unroll
        for (int k = 0; k < 32; ++k) a += sh3[n2][k] * dws[k * 16 + j];
        out[(size_t)(blockIdx.x * 4 + n2) * 16 + j] = a;
    }
}

extern "C" void kernel_launch(void* const* d_in, const int* in_sizes, int n_in,
                              void* d_out, int out_size, void* d_ws, size_t ws_size,
                              hipStream_t stream) {
    const float* X    = (const float*)d_in[0];
    const int*   edge = (const int*)d_in[1];
    const float* emb  = (const float*)d_in[2];
    const float* W1   = (const float*)d_in[3];
    const float* b1   = (const float*)d_in[4];
    const float* W2   = (const float*)d_in[5];
    const float* b2   = (const float*)d_in[6];
    const float* dW   = (const float*)d_in[7];
    float*       out  = (float*)d_out;

    char* ws = (char*)d_ws;
    int*            cnt  = (int*)(ws + OFF_CNT);
    int*            flag = (int*)(ws + OFF_FLAG);
    float*          dinv = (float*)(ws + OFF_DINV);
    int*            rs   = (int*)(ws + OFF_RS);
    int*            cur  = (int*)(ws + OFF_CUR);
    int*            csr  = (int*)(ws + OFF_CSR);
    unsigned short* embT = (unsigned short*)(ws + OFF_EMBT);
    float*          g1   = (float*)(ws + OFF_EMBT);  // reuse after GEMM1 consumed embT
    float*          P    = (float*)(ws + OFF_P);
    float*          H2   = (float*)(ws + OFF_H2);
    float*          g2   = (float*)(ws + OFF_G2);

    hipMemsetAsync(cnt, 0, N_NODES * sizeof(int), stream);

    k_sniff<<<1, 64, 0, stream>>>(edge, flag);
    k_count<<<N_EDGES / 256, 256, 0, stream>>>(edge, flag, cnt);
    k_scan<<<1, 1024, 0, stream>>>(cnt, rs, cur, dinv, embT);
    k_fill<<<N_EDGES / 256, 256, 0, stream>>>(edge, flag, cur, csr);
    k_transpose<<<dim3(157, 4), 256, 0, stream>>>(emb, embT);
    k_gemm1<<<dim3(NSPLIT, 157), 256, 0, stream>>>(X, embT, P);
    k_lin1<<<N_NODES / 16, 256, 0, stream>>>(P, W1, dinv, g1);
    k_agg1<<<N_NODES / 4, 256, 0, stream>>>(g1, rs, csr, dinv, b1, H2);
    k_lin2<<<N_NODES / 8, 256, 0, stream>>>(H2, W2, dinv, g2);
    k_agg2d<<<N_NODES / 4, 256, 0, stream>>>(g2, rs, csr, dinv, b2, dW, out);
}